// Round 5
// baseline (3193.062 us; speedup 1.0000x reference)
//
#include <hip/hip_runtime.h>
#include <hip/hip_bf16.h>
#include <cstdint>

// Problem constants
#define NB     16384   // batch
#define DIN    1024
#define HID    2048
#define NE     8
#define NC     8
#define DZ     256

// R10 main GEMM: 256x256 block tile, 8 waves (2M x 4N), wave tile 128x64,
// BK=32, TWO 32KB LDS buffers (2-deep), 2 blocks/CU (grid 512).
// R5-R9 all plateaued at 44-46% MfmaUtil across 5 schedules; the invariant
// was 8 waves/CU lockstep -> MFMA phase and LDS-read/stage phase serialize
// (1240 + ~1400 cyc per round = measured 2648). Two independent blocks/CU
// give natural phase offset so one block's MFMA hides the other's reads.
// Body/swizzle identical to R7 (best, 565us); only depth/grid/LDS changed.
#define BK2    32
#define NKT    (DIN / BK2)   // 32
#define GRID_MAIN 512        // 2 blocks/CU persistent

typedef short bf16x8 __attribute__((ext_vector_type(8)));
typedef float f32x4  __attribute__((ext_vector_type(4)));

__device__ __forceinline__ unsigned short f2bf(float f) {
    unsigned int u = __float_as_uint(f);
    unsigned int r = (u + 0x7FFFu + ((u >> 16) & 1u)) >> 16;
    return (unsigned short)r;
}

__device__ __forceinline__ void async_copy16(const void* g, void* l) {
    __builtin_amdgcn_global_load_lds(
        (const __attribute__((address_space(1))) unsigned int*)g,
        (__attribute__((address_space(3))) unsigned int*)l, 16, 0, 0);
}

// ---------------------------------------------------------------------------
// Gate: w = softmax(cos_sim(z, mu)/tau). One wave per row. Also initializes
// logits[b,c] = sum_e w[b,e]*b2[e,c]  (b2 folded here so moe_main only adds
// the GEMM part).
// ---------------------------------------------------------------------------
__global__ __launch_bounds__(256) void k_gate(const float* __restrict__ z,
                                              const float* __restrict__ mu,
                                              const int* __restrict__ tau_i,
                                              const float* __restrict__ b2,
                                              float* __restrict__ wout,
                                              float* __restrict__ logits) {
    int row = blockIdx.x * 4 + (threadIdx.x >> 6);
    int l = threadIdx.x & 63;
    float4 zv = *(const float4*)&z[(size_t)row * DZ + l * 4];
    float zz = zv.x * zv.x + zv.y * zv.y + zv.z * zv.z + zv.w * zv.w;
    float dots[NE], mm[NE];
#pragma unroll
    for (int e = 0; e < NE; ++e) {
        float4 m = *(const float4*)&mu[e * DZ + l * 4];
        dots[e] = zv.x * m.x + zv.y * m.y + zv.z * m.z + zv.w * m.w;
        mm[e]   = m.x * m.x + m.y * m.y + m.z * m.z + m.w * m.w;
    }
#pragma unroll
    for (int off = 32; off; off >>= 1) {
        zz += __shfl_xor(zz, off);
#pragma unroll
        for (int e = 0; e < NE; ++e) {
            dots[e] += __shfl_xor(dots[e], off);
            mm[e]   += __shfl_xor(mm[e], off);
        }
    }
    float zn = fmaxf(sqrtf(zz), 1e-12f);
    float tau = fmaxf(1e-6f, (float)tau_i[0]);
    float s[NE], mx = -1e30f;
#pragma unroll
    for (int e = 0; e < NE; ++e) {
        s[e] = dots[e] / (zn * fmaxf(sqrtf(mm[e]), 1e-12f)) / tau;
        mx = fmaxf(mx, s[e]);
    }
    float sum = 0.f;
#pragma unroll
    for (int e = 0; e < NE; ++e) { s[e] = expf(s[e] - mx); sum += s[e]; }
    float inv = 1.f / sum;
    if (l < NE) {
        wout[(size_t)row * NE + l] = s[l] * inv;
        float acc = 0.f;
#pragma unroll
        for (int e = 0; e < NE; ++e) acc += s[e] * inv * b2[e * NC + l];
        logits[(size_t)row * NC + l] = acc;
    }
}

// ---------------------------------------------------------------------------
// LayerNorm (shared part) -> bf16 xhat. One block per row.
// ---------------------------------------------------------------------------
__global__ __launch_bounds__(256) void k_ln(const float* __restrict__ feat,
                                            unsigned short* __restrict__ xhat) {
    int row = blockIdx.x;
    int t = threadIdx.x;
    float4 v = *(const float4*)&feat[(size_t)row * DIN + t * 4];
    float s  = v.x + v.y + v.z + v.w;
    float sq = v.x * v.x + v.y * v.y + v.z * v.z + v.w * v.w;
#pragma unroll
    for (int off = 32; off; off >>= 1) {
        s  += __shfl_down(s, off);
        sq += __shfl_down(sq, off);
    }
    __shared__ float ls[8];
    int w = t >> 6, l = t & 63;
    if (l == 0) { ls[w] = s; ls[4 + w] = sq; }
    __syncthreads();
    s  = ls[0] + ls[1] + ls[2] + ls[3];
    sq = ls[4] + ls[5] + ls[6] + ls[7];
    float mean = s * (1.f / DIN);
    float var  = sq * (1.f / DIN) - mean * mean;
    float r = 1.0f / sqrtf(var + 1e-5f);
    uint2 p;
    p.x = (unsigned)f2bf((v.x - mean) * r) | ((unsigned)f2bf((v.y - mean) * r) << 16);
    p.y = (unsigned)f2bf((v.z - mean) * r) | ((unsigned)f2bf((v.w - mean) * r) << 16);
    *(uint2*)&xhat[(size_t)row * DIN + t * 4] = p;
}

// ---------------------------------------------------------------------------
// W2 transpose->bf16 (padded [E][16][HID]) and b1p init.
// ---------------------------------------------------------------------------
__global__ __launch_bounds__(256) void k_w2prep(const float* __restrict__ W2,
                                                const float* __restrict__ b1,
                                                unsigned short* __restrict__ w2t,
                                                float* __restrict__ b1p) {
    int i = blockIdx.x * 256 + threadIdx.x;   // 8*16*2048 = 262144
    int e = i >> 15;
    int rem = i & 32767;
    int c = rem >> 11;
    int h = rem & 2047;
    float v = (c < NC) ? W2[((size_t)(e * HID + h)) * NC + c] : 0.f;
    w2t[i] = f2bf(v);
    if (i < NE * HID) b1p[i] = b1[i];
}

// ---------------------------------------------------------------------------
// W1 fold+transpose: W1t[e][h][d] = bf16(gamma[e][d] * W1[e][d][h]);
// b1p[e][h] += sum_d beta[e][d]*W1[e][d][h].  64x64 LDS tile transpose.
// ---------------------------------------------------------------------------
__global__ __launch_bounds__(256) void k_w1prep(const float* __restrict__ W1,
                                                const float* __restrict__ gamma,
                                                const float* __restrict__ beta,
                                                unsigned short* __restrict__ w1t,
                                                float* __restrict__ b1p) {
    __shared__ float tile[64][65];   // [h-local][d-local], unscaled
    int e  = blockIdx.z;
    int d0 = blockIdx.y * 64;
    int h0 = blockIdx.x * 64;
    int tx = threadIdx.x & 15, ty = threadIdx.x >> 4;
#pragma unroll
    for (int rr = 0; rr < 4; ++rr) {
        int d = ty + rr * 16;
        float4 v = *(const float4*)&W1[((size_t)e * DIN + d0 + d) * HID + h0 + tx * 4];
        tile[tx * 4 + 0][d] = v.x;
        tile[tx * 4 + 1][d] = v.y;
        tile[tx * 4 + 2][d] = v.z;
        tile[tx * 4 + 3][d] = v.w;
    }
    __syncthreads();
    float4 g = *(const float4*)&gamma[(size_t)e * DIN + d0 + tx * 4];
#pragma unroll
    for (int rr = 0; rr < 4; ++rr) {
        int h = ty + rr * 16;
        uint2 p;
        p.x = (unsigned)f2bf(tile[h][tx * 4 + 0] * g.x) |
              ((unsigned)f2bf(tile[h][tx * 4 + 1] * g.y) << 16);
        p.y = (unsigned)f2bf(tile[h][tx * 4 + 2] * g.z) |
              ((unsigned)f2bf(tile[h][tx * 4 + 3] * g.w) << 16);
        *(uint2*)&w1t[((size_t)e * HID + h0 + h) * DIN + d0 + tx * 4] = p;
    }
    if (threadIdx.x < 64) {
        int h = threadIdx.x;
        float sacc = 0.f;
        for (int r = 0; r < 64; ++r)
            sacc += beta[(size_t)e * DIN + d0 + r] * tile[h][r];
        atomicAdd(&b1p[(size_t)e * HID + h0 + h], sacc);
    }
}

// ---------------------------------------------------------------------------
// Fused main kernel, R10.
// Per K-tile: {WAITV(0) [own 4 staging loads, issued a full round earlier];
// s_barrier [collectively publishes tile kt]; stage kt+1 into buf (kt+1)&1;
// 12 swizzled ds_read_b128 + 32 MFMA (setprio-wrapped)}.  Swizzle
// f(row)=(row>>1)&3 (conflict-free, verified R7).  Expert==XCD pinning.
// Each block: one 256-row batch tile x 8 hid-chunks, acc2 across chunks,
// one cross-wave reduction + gated atomicAdd at the end.
// ht (wave-private, epilogue-only) overlays the staging buffers: fenced by
// __syncthreads after the drained last round and before the next chunk's
// prologue STAGE.
// ---------------------------------------------------------------------------

#define WAITV(n_) asm volatile("s_waitcnt vmcnt(" #n_ ")" ::: "memory")
#define BAR()  do { __builtin_amdgcn_s_barrier(); __builtin_amdgcn_sched_barrier(0); } while (0)

// stage one 256x32 A-tile + 256x32 B-tile (32KB) into buffer (tile&1).
#define STAGE(tile_) do {                                                     \
    char* dst_ = (char*)lds + (((tile_) & 1) << 15) + (t << 4);               \
    const size_t ro_ = rowoff + (size_t)(tile_) * BK2;                        \
    async_copy16(gA + ro_, dst_);                                             \
    async_copy16(gA + ro_ + (size_t)128 * DIN, dst_ + 8192);                  \
    async_copy16(gB + ro_, dst_ + 16384);                                     \
    async_copy16(gB + ro_ + (size_t)128 * DIN, dst_ + 24576);                 \
} while (0)

#define KBODY(kt_) do {                                                       \
    const short* la_ = (const short*)(lds + (((kt_) & 1) << 15));             \
    const short* lb_ = la_ + 8192;                                            \
    bf16x8 bF_[4];                                                            \
    _Pragma("unroll")                                                         \
    for (int j_ = 0; j_ < 4; ++j_)                                            \
        bF_[j_] = *(const bf16x8*)&lb_[(wn + 16 * j_ + ml) * BK2 + cswz];     \
    __builtin_amdgcn_s_setprio(1);                                            \
    _Pragma("unroll")                                                         \
    for (int i_ = 0; i_ < 8; ++i_) {                                          \
        const bf16x8 aF_ = *(const bf16x8*)&la_[(wm + 16 * i_ + ml) * BK2 + cswz]; \
        _Pragma("unroll")                                                     \
        for (int j_ = 0; j_ < 4; ++j_)                                        \
            acc[i_][j_] = __builtin_amdgcn_mfma_f32_16x16x32_bf16(            \
                aF_, bF_[j_], acc[i_][j_], 0, 0, 0);                          \
    }                                                                         \
    __builtin_amdgcn_s_setprio(0);                                            \
} while (0)

__global__ __launch_bounds__(512, 4) void moe_main(
        const unsigned short* __restrict__ xhat,   // [B][DIN] bf16
        const unsigned short* __restrict__ w1t,    // [E][HID][DIN] bf16
        const float* __restrict__ b1p,             // [E][HID]
        const unsigned short* __restrict__ w2t,    // [E][16][HID] bf16 (c>=8 zero)
        const float* __restrict__ wg,              // [B][NE]
        float* __restrict__ logits) {              // [B][NC]
    __shared__ __align__(16) char lds[65536];      // 2 x (16KB A + 16KB B)

    const int t  = threadIdx.x;
    const int w  = t >> 6, l = t & 63;
    const int q  = l >> 4, ml = l & 15;
    const int wm = (w >> 2) * 128;       // wave's hid offset in 256 tile
    const int wn = (w & 3) * 64;         // wave's batch offset in 256 tile
    const int cswz = (q ^ ((ml >> 1) & 3)) * 8;   // swizzled frag k-chunk (elems)
    const int srow = t >> 2;             // staging row 0..127
    const size_t rowoff = (size_t)srow * DIN +
                          (size_t)(((t & 3) ^ ((srow >> 1) & 3)) * 8);

    const int e    = blockIdx.x & 7;     // expert == XCD (bid%8 -> XCD)
    const int slot = blockIdx.x >> 3;    // 0..63
    const int b0   = slot * 256;
    const unsigned short* gB = xhat + (size_t)b0 * DIN;
    char* myht = (char*)lds + w * 5120;  // per-wave 64x80B hT (overlays bufs)

    f32x4 acc2[4];
#pragma unroll
    for (int tb = 0; tb < 4; ++tb) acc2[tb] = (f32x4){0.f, 0.f, 0.f, 0.f};

    for (int ms = 0; ms < 8; ++ms) {
        const int hid0 = ms * 256;
        const unsigned short* gA = w1t + ((size_t)e * HID + hid0) * DIN;

        f32x4 acc[8][4];
#pragma unroll
        for (int i = 0; i < 8; ++i)
#pragma unroll
            for (int j = 0; j < 4; ++j) acc[i][j] = (f32x4){0.f, 0.f, 0.f, 0.f};

        STAGE(0);
#pragma unroll 1
        for (int kt = 0; kt < NKT - 1; ++kt) {   // kt = 0..30
            WAITV(0);        // own slice of tile kt complete
            BAR();           // collectively: tile kt published, buf (kt+1)&1 free
            STAGE(kt + 1);
            KBODY(kt);
        }
        WAITV(0); BAR(); KBODY(31);

        // ---- epilogue: bias+ReLU -> ht, second GEMM (32-hid slabs) ----
        __syncthreads();   // all waves done reading bufs; DMA fully drained
#pragma unroll
        for (int s = 0; s < 4; ++s) {
#pragma unroll
            for (int i2 = 0; i2 < 2; ++i2) {
                const int i = 2 * s + i2;
                const float4 bias = *(const float4*)
                    &b1p[(size_t)e * HID + hid0 + wm + 16 * i + 4 * q];
#pragma unroll
                for (int j = 0; j < 4; ++j) {
                    float v0 = fmaxf(acc[i][j].x + bias.x, 0.f);
                    float v1 = fmaxf(acc[i][j].y + bias.y, 0.f);
                    float v2 = fmaxf(acc[i][j].z + bias.z, 0.f);
                    float v3 = fmaxf(acc[i][j].w + bias.w, 0.f);
                    uint2 p;
                    p.x = (unsigned)f2bf(v0) | ((unsigned)f2bf(v1) << 16);
                    p.y = (unsigned)f2bf(v2) | ((unsigned)f2bf(v3) << 16);
                    *(uint2*)(myht + (16 * j + ml) * 80 + (16 * i2 + 4 * q) * 2) = p;
                }
            }
            const bf16x8 b2f = *(const bf16x8*)&w2t[((size_t)e * 16 + ml) * HID +
                                                    hid0 + wm + 32 * s + 8 * q];
#pragma unroll
            for (int tb = 0; tb < 4; ++tb) {
                const bf16x8 a2f =
                    *(const bf16x8*)(myht + (16 * tb + ml) * 80 + q * 16);
                acc2[tb] = __builtin_amdgcn_mfma_f32_16x16x32_bf16(
                    a2f, b2f, acc2[tb], 0, 0, 0);
            }
        }
        __syncthreads();   // ht reads done before next chunk's STAGE(0) lands
    }

    // ---- cross-wave (hid-half) reduction of acc2, gated atomic store ----
    float* red = (float*)lds;
    if (w >= 4) {
        float* dst = red + ((w & 3) * 64 + l) * 16;
#pragma unroll
        for (int tb = 0; tb < 4; ++tb)
#pragma unroll
            for (int r = 0; r < 4; ++r) dst[tb * 4 + r] = acc2[tb][r];
    }
    __syncthreads();
    if (w < 4) {
        const float* src = red + (w * 64 + l) * 16;
        if (ml < NC) {
#pragma unroll
            for (int tb = 0; tb < 4; ++tb) {
#pragma unroll
                for (int r = 0; r < 4; ++r) {
                    float v = acc2[tb][r] + src[tb * 4 + r];
                    const int bg = b0 + wn + 16 * tb + 4 * q + r;
                    atomicAdd(&logits[(size_t)bg * NC + ml],
                              wg[(size_t)bg * NE + e] * v);
                }
            }
        }
    }
}

// ---------------------------------------------------------------------------
extern "C" void kernel_launch(void* const* d_in, const int* in_sizes, int n_in,
                              void* d_out, int out_size, void* d_ws, size_t ws_size,
                              hipStream_t stream) {
    const float* feat  = (const float*)d_in[0];
    const float* z     = (const float*)d_in[1];
    const float* mu    = (const float*)d_in[2];
    const float* gamma = (const float*)d_in[3];
    const float* beta  = (const float*)d_in[4];
    const float* W1    = (const float*)d_in[5];
    const float* b1    = (const float*)d_in[6];
    const float* W2    = (const float*)d_in[7];
    const float* b2    = (const float*)d_in[8];
    const int*   tau   = (const int*)d_in[9];

    float* logits = (float*)d_out;                 // [B][NC]
    float* wout   = logits + (size_t)NB * NC;      // [B][NE]

    char* ws = (char*)d_ws;
    unsigned short* xhat = (unsigned short*)ws;                       // 33.5 MB
    unsigned short* w1t  = (unsigned short*)(ws + 33554432);          // 33.5 MB
    unsigned short* w2t  = (unsigned short*)(ws + 67108864);          // 0.5 MB
    float*          b1p  = (float*)(ws + 67633152);                   // 64 KB

    k_gate<<<NB / 4, 256, 0, stream>>>(z, mu, tau, b2, wout, logits);
    k_ln<<<NB, 256, 0, stream>>>(feat, xhat);
    k_w2prep<<<(NE * 16 * HID) / 256, 256, 0, stream>>>(W2, b1, w2t, b1p);
    k_w1prep<<<dim3(HID / 64, DIN / 64, NE), 256, 0, stream>>>(W1, gamma, beta, w1t, b1p);
    moe_main<<<dim3(GRID_MAIN), 512, 0, stream>>>(xhat, w1t, b1p, w2t, wout, logits);
}

// Round 6
// 692.272 us; speedup vs baseline: 4.6124x; 4.6124x over previous
//
#include <hip/hip_runtime.h>
#include <hip/hip_bf16.h>
#include <cstdint>

// Problem constants
#define NB     16384   // batch
#define DIN    1024
#define HID    2048
#define NE     8
#define NC     8
#define DZ     256

// R11 main GEMM: 256x256 block tile, 8 waves (2M x 4N), wave tile 128x64,
// BK=64, TWO 64KB LDS buffers, 1 block/CU.  R7 body (best measured, 565us)
// with per-round fixed costs halved (rounds 32->16 per chunk) and the per-ms
// pipeline drain removed (round 15 stages the next chunk's tile 0).
// R10 lesson: 128x64 wave tiles need ~230 regs -> 2 waves/SIMD is a hard
// cap; launch_bounds(512,4) spilled acc to scratch (7.7GB scratch writes).
// Swizzle for 128B rows: phys_chunk = logical ^ (row&7) (free 2-way).
#define BK2    64
#define NKT    (DIN / BK2)   // 16
#define GRID_MAIN 256        // 1 block/CU persistent

typedef short bf16x8 __attribute__((ext_vector_type(8)));
typedef float f32x4  __attribute__((ext_vector_type(4)));

__device__ __forceinline__ unsigned short f2bf(float f) {
    unsigned int u = __float_as_uint(f);
    unsigned int r = (u + 0x7FFFu + ((u >> 16) & 1u)) >> 16;
    return (unsigned short)r;
}

__device__ __forceinline__ void async_copy16(const void* g, void* l) {
    __builtin_amdgcn_global_load_lds(
        (const __attribute__((address_space(1))) unsigned int*)g,
        (__attribute__((address_space(3))) unsigned int*)l, 16, 0, 0);
}

// ---------------------------------------------------------------------------
// Fused pre-pass: blocks [0,NB) do LayerNorm->bf16 xhat (one block/row);
// blocks [NB, NB+NB/4) do the gate (4 rows/block) and fold b2 into logits.
// ---------------------------------------------------------------------------
__global__ __launch_bounds__(256) void k_pre(const float* __restrict__ feat,
                                             unsigned short* __restrict__ xhat,
                                             const float* __restrict__ z,
                                             const float* __restrict__ mu,
                                             const int* __restrict__ tau_i,
                                             const float* __restrict__ b2,
                                             float* __restrict__ wout,
                                             float* __restrict__ logits) {
    if (blockIdx.x < NB) {
        // ---- LayerNorm (shared part) ----
        int row = blockIdx.x;
        int t = threadIdx.x;
        float4 v = *(const float4*)&feat[(size_t)row * DIN + t * 4];
        float s  = v.x + v.y + v.z + v.w;
        float sq = v.x * v.x + v.y * v.y + v.z * v.z + v.w * v.w;
#pragma unroll
        for (int off = 32; off; off >>= 1) {
            s  += __shfl_down(s, off);
            sq += __shfl_down(sq, off);
        }
        __shared__ float ls[8];
        int w = t >> 6, l = t & 63;
        if (l == 0) { ls[w] = s; ls[4 + w] = sq; }
        __syncthreads();
        s  = ls[0] + ls[1] + ls[2] + ls[3];
        sq = ls[4] + ls[5] + ls[6] + ls[7];
        float mean = s * (1.f / DIN);
        float var  = sq * (1.f / DIN) - mean * mean;
        float r = 1.0f / sqrtf(var + 1e-5f);
        uint2 p;
        p.x = (unsigned)f2bf((v.x - mean) * r) | ((unsigned)f2bf((v.y - mean) * r) << 16);
        p.y = (unsigned)f2bf((v.z - mean) * r) | ((unsigned)f2bf((v.w - mean) * r) << 16);
        *(uint2*)&xhat[(size_t)row * DIN + t * 4] = p;
    } else {
        // ---- gate: softmax(cos_sim(z,mu)/tau); logits init = sum_e w*b2 ----
        int row = (blockIdx.x - NB) * 4 + (threadIdx.x >> 6);
        int l = threadIdx.x & 63;
        float4 zv = *(const float4*)&z[(size_t)row * DZ + l * 4];
        float zz = zv.x * zv.x + zv.y * zv.y + zv.z * zv.z + zv.w * zv.w;
        float dots[NE], mm[NE];
#pragma unroll
        for (int e = 0; e < NE; ++e) {
            float4 m = *(const float4*)&mu[e * DZ + l * 4];
            dots[e] = zv.x * m.x + zv.y * m.y + zv.z * m.z + zv.w * m.w;
            mm[e]   = m.x * m.x + m.y * m.y + m.z * m.z + m.w * m.w;
        }
#pragma unroll
        for (int off = 32; off; off >>= 1) {
            zz += __shfl_xor(zz, off);
#pragma unroll
            for (int e = 0; e < NE; ++e) {
                dots[e] += __shfl_xor(dots[e], off);
                mm[e]   += __shfl_xor(mm[e], off);
            }
        }
        float zn = fmaxf(sqrtf(zz), 1e-12f);
        float tau = fmaxf(1e-6f, (float)tau_i[0]);
        float s[NE], mx = -1e30f;
#pragma unroll
        for (int e = 0; e < NE; ++e) {
            s[e] = dots[e] / (zn * fmaxf(sqrtf(mm[e]), 1e-12f)) / tau;
            mx = fmaxf(mx, s[e]);
        }
        float sum = 0.f;
#pragma unroll
        for (int e = 0; e < NE; ++e) { s[e] = expf(s[e] - mx); sum += s[e]; }
        float inv = 1.f / sum;
        if (l < NE) {
            wout[(size_t)row * NE + l] = s[l] * inv;
            float acc = 0.f;
#pragma unroll
            for (int e = 0; e < NE; ++e) acc += s[e] * inv * b2[e * NC + l];
            logits[(size_t)row * NC + l] = acc;
        }
    }
}

// ---------------------------------------------------------------------------
// W2 transpose->bf16 (padded [E][16][HID]) and b1p init.
// ---------------------------------------------------------------------------
__global__ __launch_bounds__(256) void k_w2prep(const float* __restrict__ W2,
                                                const float* __restrict__ b1,
                                                unsigned short* __restrict__ w2t,
                                                float* __restrict__ b1p) {
    int i = blockIdx.x * 256 + threadIdx.x;   // 8*16*2048 = 262144
    int e = i >> 15;
    int rem = i & 32767;
    int c = rem >> 11;
    int h = rem & 2047;
    float v = (c < NC) ? W2[((size_t)(e * HID + h)) * NC + c] : 0.f;
    w2t[i] = f2bf(v);
    if (i < NE * HID) b1p[i] = b1[i];
}

// ---------------------------------------------------------------------------
// W1 fold+transpose: W1t[e][h][d] = bf16(gamma[e][d] * W1[e][d][h]);
// b1p[e][h] += sum_d beta[e][d]*W1[e][d][h].  64x64 LDS tile transpose.
// ---------------------------------------------------------------------------
__global__ __launch_bounds__(256) void k_w1prep(const float* __restrict__ W1,
                                                const float* __restrict__ gamma,
                                                const float* __restrict__ beta,
                                                unsigned short* __restrict__ w1t,
                                                float* __restrict__ b1p) {
    __shared__ float tile[64][65];   // [h-local][d-local], unscaled
    int e  = blockIdx.z;
    int d0 = blockIdx.y * 64;
    int h0 = blockIdx.x * 64;
    int tx = threadIdx.x & 15, ty = threadIdx.x >> 4;
#pragma unroll
    for (int rr = 0; rr < 4; ++rr) {
        int d = ty + rr * 16;
        float4 v = *(const float4*)&W1[((size_t)e * DIN + d0 + d) * HID + h0 + tx * 4];
        tile[tx * 4 + 0][d] = v.x;
        tile[tx * 4 + 1][d] = v.y;
        tile[tx * 4 + 2][d] = v.z;
        tile[tx * 4 + 3][d] = v.w;
    }
    __syncthreads();
    float4 g = *(const float4*)&gamma[(size_t)e * DIN + d0 + tx * 4];
#pragma unroll
    for (int rr = 0; rr < 4; ++rr) {
        int h = ty + rr * 16;
        uint2 p;
        p.x = (unsigned)f2bf(tile[h][tx * 4 + 0] * g.x) |
              ((unsigned)f2bf(tile[h][tx * 4 + 1] * g.y) << 16);
        p.y = (unsigned)f2bf(tile[h][tx * 4 + 2] * g.z) |
              ((unsigned)f2bf(tile[h][tx * 4 + 3] * g.w) << 16);
        *(uint2*)&w1t[((size_t)e * HID + h0 + h) * DIN + d0 + tx * 4] = p;
    }
    if (threadIdx.x < 64) {
        int h = threadIdx.x;
        float sacc = 0.f;
        for (int r = 0; r < 64; ++r)
            sacc += beta[(size_t)e * DIN + d0 + r] * tile[h][r];
        atomicAdd(&b1p[(size_t)e * HID + h0 + h], sacc);
    }
}

// ---------------------------------------------------------------------------
// Fused main kernel, R11.
// Per round (BK=64): {WAITV(0) [own 8 copies, issued one full round ago];
// s_barrier [publishes tile kt, frees opposite buffer]; stage next tile (8
// DMA); 24 swizzled ds_read_b128 + 64 MFMA in two k-halves}.  Round 15
// stages the NEXT ms/pr chunk's tile 0 -> no drain at chunk boundaries.
// LDS map: [0,64K) buf0, [64K,128K) buf1; epilogue ht (40KB) and reduction
// red (16KB) overlay buf1 -- safe: ht written only after the post-round-15
// barrier (all buf1 reads done), and DMA in flight at that time targets
// buf0 only; next round-0's head barrier orders ht/red readers before the
// next DMA into buf1.
// ---------------------------------------------------------------------------

#define WAITV(n_) asm volatile("s_waitcnt vmcnt(" #n_ ")" ::: "memory")
#define BAR()  do { __builtin_amdgcn_s_barrier(); __builtin_amdgcn_sched_barrier(0); } while (0)

// stage one 256x64 A-tile + 256x64 B-tile (128KB total over 512 thr: 8x16B
// per thread) into buffer par_.  Thread t covers rows (n*64 + (t>>3)), phys
// 16B-chunk (t&7) <- logical chunk (t&7)^((t>>3)&7).
#define STAGE(gAp_, gBp_, kt64_, par_) do {                                   \
    char* da_ = (char*)lds + ((par_) << 16) + (t << 4);                       \
    const size_t ko_ = sbase + (size_t)(kt64_) * BK2;                         \
    async_copy16((gAp_) + ko_,          da_);                                 \
    async_copy16((gAp_) + ko_ + 65536,  da_ + 8192);                          \
    async_copy16((gAp_) + ko_ + 131072, da_ + 16384);                         \
    async_copy16((gAp_) + ko_ + 196608, da_ + 24576);                         \
    async_copy16((gBp_) + ko_,          da_ + 32768);                         \
    async_copy16((gBp_) + ko_ + 65536,  da_ + 40960);                         \
    async_copy16((gBp_) + ko_ + 131072, da_ + 49152);                         \
    async_copy16((gBp_) + ko_ + 196608, da_ + 57344);                         \
} while (0)

// 64 MFMA on buffer par_ in two k-halves (csw0, csw0^32).
#define KBODY(par_) do {                                                      \
    const short* la_ = (const short*)(lds + ((par_) << 16));                  \
    const short* lb_ = la_ + 16384;                                           \
    {                                                                         \
        bf16x8 bF_[4];                                                        \
        _Pragma("unroll")                                                     \
        for (int j_ = 0; j_ < 4; ++j_)                                        \
            bF_[j_] = *(const bf16x8*)&lb_[(wn + 16 * j_ + ml) * BK2 + csw0]; \
        __builtin_amdgcn_s_setprio(1);                                        \
        _Pragma("unroll")                                                     \
        for (int i_ = 0; i_ < 8; ++i_) {                                      \
            const bf16x8 aF_ =                                                \
                *(const bf16x8*)&la_[(wm + 16 * i_ + ml) * BK2 + csw0];       \
            _Pragma("unroll")                                                 \
            for (int j_ = 0; j_ < 4; ++j_)                                    \
                acc[i_][j_] = __builtin_amdgcn_mfma_f32_16x16x32_bf16(        \
                    aF_, bF_[j_], acc[i_][j_], 0, 0, 0);                      \
        }                                                                     \
        __builtin_amdgcn_s_setprio(0);                                        \
    }                                                                         \
    {                                                                         \
        const int cs1_ = csw0 ^ 32;                                           \
        bf16x8 bF_[4];                                                        \
        _Pragma("unroll")                                                     \
        for (int j_ = 0; j_ < 4; ++j_)                                        \
            bF_[j_] = *(const bf16x8*)&lb_[(wn + 16 * j_ + ml) * BK2 + cs1_]; \
        __builtin_amdgcn_s_setprio(1);                                        \
        _Pragma("unroll")                                                     \
        for (int i_ = 0; i_ < 8; ++i_) {                                      \
            const bf16x8 aF_ =                                                \
                *(const bf16x8*)&la_[(wm + 16 * i_ + ml) * BK2 + cs1_];       \
            _Pragma("unroll")                                                 \
            for (int j_ = 0; j_ < 4; ++j_)                                    \
                acc[i_][j_] = __builtin_amdgcn_mfma_f32_16x16x32_bf16(        \
                    aF_, bF_[j_], acc[i_][j_], 0, 0, 0);                      \
        }                                                                     \
        __builtin_amdgcn_s_setprio(0);                                        \
    }                                                                         \
} while (0)

__global__ __launch_bounds__(512, 2) void moe_main(
        const unsigned short* __restrict__ xhat,   // [B][DIN] bf16
        const unsigned short* __restrict__ w1t,    // [E][HID][DIN] bf16
        const float* __restrict__ b1p,             // [E][HID]
        const unsigned short* __restrict__ w2t,    // [E][16][HID] bf16 (c>=8 zero)
        const float* __restrict__ wg,              // [B][NE]
        float* __restrict__ logits) {              // [B][NC]
    __shared__ __align__(16) char lds[131072];     // 2 x (32KB A + 32KB B)

    const int t  = threadIdx.x;
    const int w  = t >> 6, l = t & 63;
    const int q  = l >> 4, ml = l & 15;
    const int wm = (w >> 2) * 128;       // wave's hid offset in 256 tile
    const int wn = (w & 3) * 64;         // wave's batch offset in 256 tile
    const int csw0 = (q ^ (ml & 7)) * 8; // swizzled frag chunk, k-half 0
    const size_t sbase = (size_t)(t >> 3) * DIN +
                         (size_t)(((t & 7) ^ ((t >> 3) & 7)) * 8);

    const int e    = blockIdx.x & 7;     // expert == XCD (bid%8 -> XCD)
    const int slot = blockIdx.x >> 3;    // 0..31
    char* myht = (char*)lds + 65536 + w * 5120;  // per-wave 64x80B hT (buf1)
    const unsigned short* eA = w1t + (size_t)e * HID * DIN;

    // prologue: (pr0, ms0, tile0)
    STAGE(eA, xhat + (size_t)slot * 256 * DIN, 0, 0);

    for (int pr = 0; pr < 2; ++pr) {
        const int b0 = (pr * 32 + slot) * 256;
        const unsigned short* gB = xhat + (size_t)b0 * DIN;

        f32x4 acc2[4];
#pragma unroll
        for (int tb = 0; tb < 4; ++tb) acc2[tb] = (f32x4){0.f, 0.f, 0.f, 0.f};

        for (int ms = 0; ms < 8; ++ms) {
            const int hid0 = ms * 256;
            const unsigned short* gA = eA + (size_t)hid0 * DIN;

            f32x4 acc[8][4];
#pragma unroll
            for (int i = 0; i < 8; ++i)
#pragma unroll
                for (int j = 0; j < 4; ++j) acc[i][j] = (f32x4){0.f, 0.f, 0.f, 0.f};

#pragma unroll 1
            for (int kt = 0; kt < NKT - 1; ++kt) {   // kt = 0..14
                WAITV(0);        // own 8 copies of tile kt complete
                BAR();           // tile kt published; buf (kt+1)&1 free
                STAGE(gA, gB, kt + 1, (kt + 1) & 1);
                KBODY(kt & 1);
            }
            // round 15: compute buf1; stage next chunk's tile 0 -> buf0
            WAITV(0);
            BAR();
            if (!(pr == 1 && ms == 7)) {
                const unsigned short* gAn = (ms == 7) ? eA : gA + (size_t)256 * DIN;
                const unsigned short* gBn = (ms == 7) ? gB + (size_t)8192 * DIN : gB;
                STAGE(gAn, gBn, 0, 0);
            }
            KBODY(1);
            BAR();   // all waves done reading buf1 -> ht region writable

            // ---- epilogue: bias+ReLU -> ht, second GEMM (32-hid slabs) ----
#pragma unroll
            for (int s = 0; s < 4; ++s) {
#pragma unroll
                for (int i2 = 0; i2 < 2; ++i2) {
                    const int i = 2 * s + i2;
                    const float4 bias = *(const float4*)
                        &b1p[(size_t)e * HID + hid0 + wm + 16 * i + 4 * q];
#pragma unroll
                    for (int j = 0; j < 4; ++j) {
                        float v0 = fmaxf(acc[i][j].x + bias.x, 0.f);
                        float v1 = fmaxf(acc[i][j].y + bias.y, 0.f);
                        float v2 = fmaxf(acc[i][j].z + bias.z, 0.f);
                        float v3 = fmaxf(acc[i][j].w + bias.w, 0.f);
                        uint2 p;
                        p.x = (unsigned)f2bf(v0) | ((unsigned)f2bf(v1) << 16);
                        p.y = (unsigned)f2bf(v2) | ((unsigned)f2bf(v3) << 16);
                        *(uint2*)(myht + (16 * j + ml) * 80 + (16 * i2 + 4 * q) * 2) = p;
                    }
                }
                const bf16x8 b2f = *(const bf16x8*)&w2t[((size_t)e * 16 + ml) * HID +
                                                        hid0 + wm + 32 * s + 8 * q];
#pragma unroll
                for (int tb = 0; tb < 4; ++tb) {
                    const bf16x8 a2f =
                        *(const bf16x8*)(myht + (16 * tb + ml) * 80 + q * 16);
                    acc2[tb] = __builtin_amdgcn_mfma_f32_16x16x32_bf16(
                        a2f, b2f, acc2[tb], 0, 0, 0);
                }
            }
            // next round-0's head barrier orders ht readers vs next DMA
        }

        // ---- cross-wave (hid-half) reduction of acc2, gated atomic store ----
        __syncthreads();
        float* red = (float*)(lds + 106496);   // after ht region, inside buf1
        if (w >= 4) {
            float* dst = red + ((w & 3) * 64 + l) * 16;
#pragma unroll
            for (int tb = 0; tb < 4; ++tb)
#pragma unroll
                for (int r = 0; r < 4; ++r) dst[tb * 4 + r] = acc2[tb][r];
        }
        __syncthreads();
        if (w < 4) {
            const float* src = red + (w * 64 + l) * 16;
            if (ml < NC) {
#pragma unroll
                for (int tb = 0; tb < 4; ++tb) {
#pragma unroll
                    for (int r = 0; r < 4; ++r) {
                        float v = acc2[tb][r] + src[tb * 4 + r];
                        const int bg = b0 + wn + 16 * tb + 4 * q + r;
                        atomicAdd(&logits[(size_t)bg * NC + ml],
                                  wg[(size_t)bg * NE + e] * v);
                    }
                }
            }
        }
        // next pr's round-0 head barrier orders red readers vs new DMA
    }
}

// ---------------------------------------------------------------------------
extern "C" void kernel_launch(void* const* d_in, const int* in_sizes, int n_in,
                              void* d_out, int out_size, void* d_ws, size_t ws_size,
                              hipStream_t stream) {
    const float* feat  = (const float*)d_in[0];
    const float* z     = (const float*)d_in[1];
    const float* mu    = (const float*)d_in[2];
    const float* gamma = (const float*)d_in[3];
    const float* beta  = (const float*)d_in[4];
    const float* W1    = (const float*)d_in[5];
    const float* b1    = (const float*)d_in[6];
    const float* W2    = (const float*)d_in[7];
    const float* b2    = (const float*)d_in[8];
    const int*   tau   = (const int*)d_in[9];

    float* logits = (float*)d_out;                 // [B][NC]
    float* wout   = logits + (size_t)NB * NC;      // [B][NE]

    char* ws = (char*)d_ws;
    unsigned short* xhat = (unsigned short*)ws;                       // 33.5 MB
    unsigned short* w1t  = (unsigned short*)(ws + 33554432);          // 33.5 MB
    unsigned short* w2t  = (unsigned short*)(ws + 67108864);          // 0.5 MB
    float*          b1p  = (float*)(ws + 67633152);                   // 64 KB

    k_pre<<<NB + NB / 4, 256, 0, stream>>>(feat, xhat, z, mu, tau, b2, wout, logits);
    k_w2prep<<<(NE * 16 * HID) / 256, 256, 0, stream>>>(W2, b1, w2t, b1p);
    k_w1prep<<<dim3(HID / 64, DIN / 64, NE), 256, 0, stream>>>(W1, gamma, beta, w1t, b1p);
    moe_main<<<dim3(GRID_MAIN), 512, 0, stream>>>(xhat, w1t, b1p, w2t, wout, logits);
}